// Round 12
// baseline (72.756 us; speedup 1.0000x reference)
//
#include <hip/hip_runtime.h>
#include <hip/hip_fp16.h>
#include <cmath>

#define NB 32
#define CH 384
#define IH 64
#define IW 64
#define OH 32
#define OW 32
#define PR 69    // padded rows 0..68; orig row r -> pr = r+3
#define SF 18    // LDS row stride in float4 (72 floats); orig col c -> padded c+4

typedef unsigned int u32x4 __attribute__((ext_vector_type(4)));
typedef float        f32x4 __attribute__((ext_vector_type(4)));

// ---------------------------------------------------------------------------
// Pass 1: 7x7 + 3x3 depthwise conv (stride 2), one 128-thread block per
// (n,c) plane. LDS = plain fp32 padded plane, stride 72 floats; orig col c at
// padded col c+4 so staged float4s are 16B-aligned -> ds_write_b128, and each
// conv row for an (A,B) output-column pair needs padded cols 4j16+1..4j16+9
// = float4 indices j16..j16+2 -> exactly 3 ds_read_b128 per row.
// Thread = 4-row x 2-col tile: 13 rows x 3 b128 = 39 LDS reads per 8 outputs
// (vs 117 b32 in the quad-split layout). Bank-uniform (8 lanes/bank = b128
// minimum). FMA schedule identical to the proven R10 kernel (fp32 math).
// Outputs packed half2{y_lk,y_sk}; per-wave stats -> partials slab (plain
// stores, every slot written every call -> no memset).
// ---------------------------------------------------------------------------
__global__ __launch_bounds__(128, 4) void conv_stats_kernel(
    const float* __restrict__ x,
    const float* __restrict__ w_lk,
    const float* __restrict__ w_sk,
    uint2* __restrict__ yls,        // [planes][OH*OW/2] packed pairs
    float* __restrict__ partial)    // [CH][NB][2][4] per-wave partial sums
{
    __shared__ float4 sxf[PR][SF];

    const int nc  = blockIdx.x;
    const int n   = nc / CH;
    const int c   = nc % CH;
    const int tid = threadIdx.x;

    // ---- issue all staging loads first (HBM latency hides under halo) ----
    const float4* xp4 = (const float4*)(x + (size_t)nc * (IH * IW));
    float4 vbuf[8];
#pragma unroll
    for (int it = 0; it < 8; ++it) vbuf[it] = xp4[tid + it * 128];

    const float4 z4 = make_float4(0.f, 0.f, 0.f, 0.f);

    // ---- zero halo only (interior fully overwritten by staging) ----
    // full rows: pr 0,1,2 (orig -3..-1) and pr 67,68 (orig 64,65)
    for (int i = tid; i < 5 * SF; i += 128) {
        const int r = i / SF, q = i % SF;
        sxf[(r < 3) ? r : (r + 64)][q] = z4;
    }
    // side float4s: idx 0 (cols 0..3: unused+left halo) and idx 17
    // (cols 68..71: right halo+pad) for rows 3..66
    {
        const int i = tid;                       // 128 slots, one per thread
        const int r = 3 + (i >> 1);
        sxf[r][(i & 1) ? 17 : 0] = z4;
    }

    // ---- scatter staged registers (aligned b128 writes) ----
#pragma unroll
    for (int it = 0; it < 8; ++it) {
        const int i = tid + it * 128;
        const int r  = (i >> 4) + 3;    // 16 float4 per 64-wide row
        const int q4 = i & 15;          // orig cols 4q4..4q4+3 -> f4 idx q4+1
        sxf[r][q4 + 1] = vbuf[it];
    }
    __syncthreads();

    // per-channel weights (block-uniform -> scalar loads)
    float wl[49], ws9[9];
#pragma unroll
    for (int t = 0; t < 49; ++t) wl[t] = w_lk[c * 49 + t];
#pragma unroll
    for (int t = 0; t < 9; ++t)  ws9[t] = w_sk[c * 9 + t];

    const int lane = tid & 63;
    const int wv   = tid >> 6;        // 0..1
    const int j16  = lane & 15;       // column-pair index
    const int g    = lane >> 4;       // 0..3 row group
    const int oy0  = (wv * 4 + g) * 4;// output rows oy0..oy0+3
    const int prb  = 2 * oy0;

    // A = col 2*j16, B = col 2*j16+1
    float alA[4] = {0.f,0.f,0.f,0.f}, alB[4] = {0.f,0.f,0.f,0.f};
    float asA[4] = {0.f,0.f,0.f,0.f}, asB[4] = {0.f,0.f,0.f,0.f};

#pragma unroll
    for (int k = 0; k < 13; ++k) {
        const int pr = prb + k;
        const float4 X0 = sxf[pr][j16];       // padded cols 4j16   .. 4j16+3
        const float4 X1 = sxf[pr][j16 + 1];   // padded cols 4j16+4 .. 4j16+7
        const float4 X2 = sxf[pr][j16 + 2];   // padded cols 4j16+8 .. 4j16+11
        // A taps (padded 4j16+1..+7): X0.y X0.z X0.w X1.x X1.y X1.z X1.w
        // B taps (padded 4j16+3..+9): X0.w X1.x X1.y X1.z X1.w X2.x X2.y
#pragma unroll
        for (int j = 0; j < 4; ++j) {
            if (k >= 2 * j && k <= 2 * j + 6) {        // folds at compile time
                const int ky = k - 2 * j;
                alA[j] = fmaf(X0.y, wl[ky * 7 + 0], alA[j]);
                alA[j] = fmaf(X0.z, wl[ky * 7 + 1], alA[j]);
                alA[j] = fmaf(X0.w, wl[ky * 7 + 2], alA[j]);
                alA[j] = fmaf(X1.x, wl[ky * 7 + 3], alA[j]);
                alA[j] = fmaf(X1.y, wl[ky * 7 + 4], alA[j]);
                alA[j] = fmaf(X1.z, wl[ky * 7 + 5], alA[j]);
                alA[j] = fmaf(X1.w, wl[ky * 7 + 6], alA[j]);
                alB[j] = fmaf(X0.w, wl[ky * 7 + 0], alB[j]);
                alB[j] = fmaf(X1.x, wl[ky * 7 + 1], alB[j]);
                alB[j] = fmaf(X1.y, wl[ky * 7 + 2], alB[j]);
                alB[j] = fmaf(X1.z, wl[ky * 7 + 3], alB[j]);
                alB[j] = fmaf(X1.w, wl[ky * 7 + 4], alB[j]);
                alB[j] = fmaf(X2.x, wl[ky * 7 + 5], alB[j]);
                alB[j] = fmaf(X2.y, wl[ky * 7 + 6], alB[j]);
            }
            if (k >= 2 * j + 2 && k <= 2 * j + 4) {
                const int ks = k - 2 * j - 2;
                // skA taps (padded 4j16+3..+5): X0.w X1.x X1.y
                // skB taps (padded 4j16+5..+7): X1.y X1.z X1.w
                asA[j] = fmaf(X0.w, ws9[ks * 3 + 0], asA[j]);
                asA[j] = fmaf(X1.x, ws9[ks * 3 + 1], asA[j]);
                asA[j] = fmaf(X1.y, ws9[ks * 3 + 2], asA[j]);
                asB[j] = fmaf(X1.y, ws9[ks * 3 + 0], asB[j]);
                asB[j] = fmaf(X1.z, ws9[ks * 3 + 1], asB[j]);
                asB[j] = fmaf(X1.w, ws9[ks * 3 + 2], asB[j]);
            }
        }
    }

    // store packed fp16 pairs, accumulate per-thread stats
    float s0 = 0.f, s1 = 0.f, s2 = 0.f, s3 = 0.f;
    uint2* yp = yls + (size_t)nc * (OH * OW / 2);
#pragma unroll
    for (int j = 0; j < 4; ++j) {
        const int oy = oy0 + j;
        const __half2 hA = __floats2half2_rn(alA[j], asA[j]);
        const __half2 hB = __floats2half2_rn(alB[j], asB[j]);
        uint2 u;
        u.x = *reinterpret_cast<const unsigned int*>(&hA);
        u.y = *reinterpret_cast<const unsigned int*>(&hB);
        yp[oy * (OW / 2) + j16] = u;
        s0 += alA[j] + alB[j];
        s1 += alA[j] * alA[j] + alB[j] * alB[j];
        s2 += asA[j] + asB[j];
        s3 += asA[j] * asA[j] + asB[j] * asB[j];
    }

    // wave64 reduce, lane 0 writes this wave's partial (no atomics)
#pragma unroll
    for (int off = 32; off >= 1; off >>= 1) {
        s0 += __shfl_down(s0, off);
        s1 += __shfl_down(s1, off);
        s2 += __shfl_down(s2, off);
        s3 += __shfl_down(s3, off);
    }
    if (lane == 0) {
        ((float4*)partial)[(c * NB + n) * 2 + wv] = make_float4(s0, s1, s2, s3);
    }
}

// ---------------------------------------------------------------------------
// Pass 2: one block per (n,c) plane (256 threads = 256 uint4 = 1024 px).
// Wave 0 reduces this channel's 256 partial floats (64 lanes x float4) via
// butterfly shuffles, lane 0 folds BN -> 4 params in LDS; all threads unpack
// 4 half2 px/uint4, affine both branches, add, exact GELU.
// yls read NT (single use); out stored NT (never re-read) -> L3 kept for x.
// ---------------------------------------------------------------------------
__global__ __launch_bounds__(256) void apply_kernel(
    const u32x4* __restrict__ yls4,
    const float* __restrict__ partial,
    const float* __restrict__ gamma_lk, const float* __restrict__ beta_lk,
    const float* __restrict__ gamma_sk, const float* __restrict__ beta_sk,
    f32x4* __restrict__ out)
{
    __shared__ float sp[4];

    const int b = blockIdx.x;
    const int c = b % CH;
    const int tid = threadIdx.x;

    if (tid < 64) {
        float4 v = ((const float4*)partial)[c * 64 + tid];
        float s0 = v.x, s1 = v.y, s2 = v.z, s3 = v.w;
#pragma unroll
        for (int off = 32; off >= 1; off >>= 1) {
            s0 += __shfl_down(s0, off);
            s1 += __shfl_down(s1, off);
            s2 += __shfl_down(s2, off);
            s3 += __shfl_down(s3, off);
        }
        if (tid == 0) {
            const float inv_cnt = 1.0f / (float)(NB * OH * OW);
            const float mean_l = s0 * inv_cnt;
            const float var_l  = s1 * inv_cnt - mean_l * mean_l;
            const float sc_l   = gamma_lk[c] * rsqrtf(var_l + 1e-5f);
            const float sh_l   = beta_lk[c] - mean_l * sc_l;
            const float mean_s = s2 * inv_cnt;
            const float var_s  = s3 * inv_cnt - mean_s * mean_s;
            const float sc_s   = gamma_sk[c] * rsqrtf(var_s + 1e-5f);
            const float sh_s   = beta_sk[c] - mean_s * sc_s;
            sp[0] = sc_l; sp[1] = sh_l; sp[2] = sc_s; sp[3] = sh_s;
        }
    }
    __syncthreads();

    const float sc_l = sp[0], sh_l = sp[1], sc_s = sp[2], sh_s = sp[3];

    const int i = b * 256 + tid;
    const u32x4 v = __builtin_nontemporal_load(yls4 + i);
    const unsigned int uv0 = v.x, uv1 = v.y, uv2 = v.z, uv3 = v.w;
    const __half2 h0 = *reinterpret_cast<const __half2*>(&uv0);
    const __half2 h1 = *reinterpret_cast<const __half2*>(&uv1);
    const __half2 h2 = *reinterpret_cast<const __half2*>(&uv2);
    const __half2 h3 = *reinterpret_cast<const __half2*>(&uv3);

    const float v0 = fmaf(__low2float(h0), sc_l, sh_l) + fmaf(__high2float(h0), sc_s, sh_s);
    const float v1 = fmaf(__low2float(h1), sc_l, sh_l) + fmaf(__high2float(h1), sc_s, sh_s);
    const float v2 = fmaf(__low2float(h2), sc_l, sh_l) + fmaf(__high2float(h2), sc_s, sh_s);
    const float v3 = fmaf(__low2float(h3), sc_l, sh_l) + fmaf(__high2float(h3), sc_s, sh_s);

    f32x4 r;
    r.x = 0.5f * v0 * (1.0f + erff(v0 * 0.70710678118654752f));
    r.y = 0.5f * v1 * (1.0f + erff(v1 * 0.70710678118654752f));
    r.z = 0.5f * v2 * (1.0f + erff(v2 * 0.70710678118654752f));
    r.w = 0.5f * v3 * (1.0f + erff(v3 * 0.70710678118654752f));
    __builtin_nontemporal_store(r, out + i);
}

extern "C" void kernel_launch(void* const* d_in, const int* in_sizes, int n_in,
                              void* d_out, int out_size, void* d_ws, size_t ws_size,
                              hipStream_t stream) {
    const float* x        = (const float*)d_in[0];
    const float* w_lk     = (const float*)d_in[1];
    const float* gamma_lk = (const float*)d_in[2];
    const float* beta_lk  = (const float*)d_in[3];
    const float* w_sk     = (const float*)d_in[4];
    const float* gamma_sk = (const float*)d_in[5];
    const float* beta_sk  = (const float*)d_in[6];
    float* out = (float*)d_out;

    float* partial = (float*)d_ws;                       // CH*NB*2*4 floats (393 KB)
    uint2* yls     = (uint2*)(partial + CH * NB * 2 * 4);// 50 MB packed fp16 pairs

    conv_stats_kernel<<<NB * CH, 128, 0, stream>>>(x, w_lk, w_sk, yls, partial);
    apply_kernel<<<NB * CH, 256, 0, stream>>>(
        (const u32x4*)yls, partial, gamma_lk, beta_lk, gamma_sk, beta_sk,
        (f32x4*)out);
}

// Round 13
// 64.439 us; speedup vs baseline: 1.1291x; 1.1291x over previous
//
#include <hip/hip_runtime.h>
#include <hip/hip_fp16.h>
#include <cmath>

#define NB 32
#define CH 384
#define IH 64
#define IW 64
#define OH 32
#define OW 32
#define PR 70    // padded rows 0..69; orig row r -> pr = r+3 (rows 0..68 used)
#define SQ 18    // quads per class-pair row

typedef unsigned int u32x4 __attribute__((ext_vector_type(4)));
typedef float        f32x4 __attribute__((ext_vector_type(4)));

// ---------------------------------------------------------------------------
// Pass 1: 7x7 + 3x3 depthwise conv (stride 2), one 128-thread block per
// (n,c) plane. LDS = fp16 class-pair layout: sx2[e][pr][q] = half2 of padded
// cols {4q+2e, 4q+2e+1}, padded col = orig col + 4. Staged float4 -> two
// clean half2 writes. Per conv row, outputs A=2*j16, B=2*j16+1 need padded
// cols 4j16+1..4j16+9 = 5 half2 reads (P0..P4) vs 9 b32 in the fp32 quad
// layout. Banks: (18*pr + q) mod 32, row-groups 8 apart -> +16g -> 32 banks
// x 2 lanes = 2-way (free). LDS/plane 10.1 KB -> 12 blocks/CU.
// Math is fp32 FMA on unpacked halves (v_fma_mix-friendly), schedule
// identical to the proven R10 kernel.
// Outputs packed half2{y_lk,y_sk}; per-wave stats -> partials slab (plain
// stores, every slot written every call -> no memset).
// ---------------------------------------------------------------------------
__global__ __launch_bounds__(128, 6) void conv_stats_kernel(
    const float* __restrict__ x,
    const float* __restrict__ w_lk,
    const float* __restrict__ w_sk,
    uint2* __restrict__ yls,        // [planes][OH*OW/2] packed pairs
    float* __restrict__ partial)    // [CH][NB][2][4] per-wave partial sums
{
    __shared__ __half2 sx2[2][PR][SQ];

    const int nc  = blockIdx.x;
    const int n   = nc / CH;
    const int c   = nc % CH;
    const int tid = threadIdx.x;

    // ---- issue all staging loads first (HBM latency hides under halo) ----
    const float4* xp4 = (const float4*)(x + (size_t)nc * (IH * IW));
    float4 vbuf[8];
#pragma unroll
    for (int it = 0; it < 8; ++it) vbuf[it] = xp4[tid + it * 128];

    const __half2 z2 = __floats2half2_rn(0.f, 0.f);

    // ---- zero halo only (interior fully overwritten by staging) ----
    // full rows pr 0,1,2 (orig -3..-1 + unused -4) and 67,68 (orig 64,65)
    for (int i = tid; i < 2 * 5 * SQ; i += 128) {
        const int e = i / (5 * SQ);
        const int rem = i % (5 * SQ);
        const int r = rem / SQ, q = rem % SQ;
        sx2[e][(r < 3) ? r : (r + 64)][q] = z2;
    }
    // side pairs for rows 3..66: (0,0) cps 0,1 ; (1,0) cps 2,3 ; (0,17) cps 68,69
    for (int i = tid; i < 64 * 3; i += 128) {
        const int r = 3 + i / 3;
        const int t = i % 3;
        if (t == 0)      sx2[0][r][0]  = z2;
        else if (t == 1) sx2[1][r][0]  = z2;
        else             sx2[0][r][17] = z2;
    }

    // ---- scatter staged registers as half2 pairs ----
    // float4 i: orig cols 4q4..4q4+3 -> cp 4q4+4..4q4+7 -> quads q4+1,
    // (v.x,v.y) -> class pair e=0, (v.z,v.w) -> e=1.
#pragma unroll
    for (int it = 0; it < 8; ++it) {
        const int i = tid + it * 128;
        const float4 v = vbuf[it];
        const int r  = (i >> 4) + 3;
        const int q4 = i & 15;
        sx2[0][r][q4 + 1] = __floats2half2_rn(v.x, v.y);
        sx2[1][r][q4 + 1] = __floats2half2_rn(v.z, v.w);
    }
    __syncthreads();

    // per-channel weights (block-uniform -> scalar loads)
    float wl[49], ws9[9];
#pragma unroll
    for (int t = 0; t < 49; ++t) wl[t] = w_lk[c * 49 + t];
#pragma unroll
    for (int t = 0; t < 9; ++t)  ws9[t] = w_sk[c * 9 + t];

    const int lane = tid & 63;
    const int wv   = tid >> 6;        // 0..1
    const int j16  = lane & 15;       // column-pair index
    const int g    = lane >> 4;       // 0..3 row group
    const int oy0  = (wv * 4 + g) * 4;// output rows oy0..oy0+3
    const int prb  = 2 * oy0;

    // A = col 2*j16, B = col 2*j16+1
    float alA[4] = {0.f,0.f,0.f,0.f}, alB[4] = {0.f,0.f,0.f,0.f};
    float asA[4] = {0.f,0.f,0.f,0.f}, asB[4] = {0.f,0.f,0.f,0.f};

#pragma unroll
    for (int k = 0; k < 13; ++k) {
        const int pr = prb + k;
        const __half2 P0 = sx2[0][pr][j16];       // cps 4j16+0, +1
        const __half2 P1 = sx2[1][pr][j16];       // cps +2, +3
        const __half2 P2 = sx2[0][pr][j16 + 1];   // cps +4, +5
        const __half2 P3 = sx2[1][pr][j16 + 1];   // cps +6, +7
        const __half2 P4 = sx2[0][pr][j16 + 2];   // cps +8, +9
        const float c1 = __high2float(P0);
        const float c2 = __low2float(P1);
        const float c3 = __high2float(P1);
        const float c4 = __low2float(P2);
        const float c5 = __high2float(P2);
        const float c6 = __low2float(P3);
        const float c7 = __high2float(P3);
        const float c8 = __low2float(P4);
        const float c9 = __high2float(P4);
#pragma unroll
        for (int j = 0; j < 4; ++j) {
            if (k >= 2 * j && k <= 2 * j + 6) {        // folds at compile time
                const int ky = k - 2 * j;
                // A taps: cps 4j16+1..+7 = c1..c7
                alA[j] = fmaf(c1, wl[ky * 7 + 0], alA[j]);
                alA[j] = fmaf(c2, wl[ky * 7 + 1], alA[j]);
                alA[j] = fmaf(c3, wl[ky * 7 + 2], alA[j]);
                alA[j] = fmaf(c4, wl[ky * 7 + 3], alA[j]);
                alA[j] = fmaf(c5, wl[ky * 7 + 4], alA[j]);
                alA[j] = fmaf(c6, wl[ky * 7 + 5], alA[j]);
                alA[j] = fmaf(c7, wl[ky * 7 + 6], alA[j]);
                // B taps: cps 4j16+3..+9 = c3..c9
                alB[j] = fmaf(c3, wl[ky * 7 + 0], alB[j]);
                alB[j] = fmaf(c4, wl[ky * 7 + 1], alB[j]);
                alB[j] = fmaf(c5, wl[ky * 7 + 2], alB[j]);
                alB[j] = fmaf(c6, wl[ky * 7 + 3], alB[j]);
                alB[j] = fmaf(c7, wl[ky * 7 + 4], alB[j]);
                alB[j] = fmaf(c8, wl[ky * 7 + 5], alB[j]);
                alB[j] = fmaf(c9, wl[ky * 7 + 6], alB[j]);
            }
            if (k >= 2 * j + 2 && k <= 2 * j + 4) {
                const int ks = k - 2 * j - 2;
                // skA taps: cps 4j16+3..+5 = c3,c4,c5 ; skB: +5..+7 = c5,c6,c7
                asA[j] = fmaf(c3, ws9[ks * 3 + 0], asA[j]);
                asA[j] = fmaf(c4, ws9[ks * 3 + 1], asA[j]);
                asA[j] = fmaf(c5, ws9[ks * 3 + 2], asA[j]);
                asB[j] = fmaf(c5, ws9[ks * 3 + 0], asB[j]);
                asB[j] = fmaf(c6, ws9[ks * 3 + 1], asB[j]);
                asB[j] = fmaf(c7, ws9[ks * 3 + 2], asB[j]);
            }
        }
    }

    // store packed fp16 pairs, accumulate per-thread stats
    float s0 = 0.f, s1 = 0.f, s2 = 0.f, s3 = 0.f;
    uint2* yp = yls + (size_t)nc * (OH * OW / 2);
#pragma unroll
    for (int j = 0; j < 4; ++j) {
        const int oy = oy0 + j;
        const __half2 hA = __floats2half2_rn(alA[j], asA[j]);
        const __half2 hB = __floats2half2_rn(alB[j], asB[j]);
        uint2 u;
        u.x = *reinterpret_cast<const unsigned int*>(&hA);
        u.y = *reinterpret_cast<const unsigned int*>(&hB);
        yp[oy * (OW / 2) + j16] = u;
        s0 += alA[j] + alB[j];
        s1 += alA[j] * alA[j] + alB[j] * alB[j];
        s2 += asA[j] + asB[j];
        s3 += asA[j] * asA[j] + asB[j] * asB[j];
    }

    // wave64 reduce, lane 0 writes this wave's partial (no atomics)
#pragma unroll
    for (int off = 32; off >= 1; off >>= 1) {
        s0 += __shfl_down(s0, off);
        s1 += __shfl_down(s1, off);
        s2 += __shfl_down(s2, off);
        s3 += __shfl_down(s3, off);
    }
    if (lane == 0) {
        ((float4*)partial)[(c * NB + n) * 2 + wv] = make_float4(s0, s1, s2, s3);
    }
}

// ---------------------------------------------------------------------------
// Pass 2: one block per (n,c) plane (256 threads = 256 uint4 = 1024 px).
// Wave 0 reduces this channel's 256 partial floats (64 lanes x float4) via
// butterfly shuffles, lane 0 folds BN -> 4 params in LDS; all threads unpack
// 4 half2 px/uint4, affine both branches, add, exact GELU.
// yls read NT (single use); out stored NT (never re-read) -> L3 kept for x.
// ---------------------------------------------------------------------------
__global__ __launch_bounds__(256) void apply_kernel(
    const u32x4* __restrict__ yls4,
    const float* __restrict__ partial,
    const float* __restrict__ gamma_lk, const float* __restrict__ beta_lk,
    const float* __restrict__ gamma_sk, const float* __restrict__ beta_sk,
    f32x4* __restrict__ out)
{
    __shared__ float sp[4];

    const int b = blockIdx.x;
    const int c = b % CH;
    const int tid = threadIdx.x;

    if (tid < 64) {
        float4 v = ((const float4*)partial)[c * 64 + tid];
        float s0 = v.x, s1 = v.y, s2 = v.z, s3 = v.w;
#pragma unroll
        for (int off = 32; off >= 1; off >>= 1) {
            s0 += __shfl_down(s0, off);
            s1 += __shfl_down(s1, off);
            s2 += __shfl_down(s2, off);
            s3 += __shfl_down(s3, off);
        }
        if (tid == 0) {
            const float inv_cnt = 1.0f / (float)(NB * OH * OW);
            const float mean_l = s0 * inv_cnt;
            const float var_l  = s1 * inv_cnt - mean_l * mean_l;
            const float sc_l   = gamma_lk[c] * rsqrtf(var_l + 1e-5f);
            const float sh_l   = beta_lk[c] - mean_l * sc_l;
            const float mean_s = s2 * inv_cnt;
            const float var_s  = s3 * inv_cnt - mean_s * mean_s;
            const float sc_s   = gamma_sk[c] * rsqrtf(var_s + 1e-5f);
            const float sh_s   = beta_sk[c] - mean_s * sc_s;
            sp[0] = sc_l; sp[1] = sh_l; sp[2] = sc_s; sp[3] = sh_s;
        }
    }
    __syncthreads();

    const float sc_l = sp[0], sh_l = sp[1], sc_s = sp[2], sh_s = sp[3];

    const int i = b * 256 + tid;
    const u32x4 v = __builtin_nontemporal_load(yls4 + i);
    const unsigned int uv0 = v.x, uv1 = v.y, uv2 = v.z, uv3 = v.w;
    const __half2 h0 = *reinterpret_cast<const __half2*>(&uv0);
    const __half2 h1 = *reinterpret_cast<const __half2*>(&uv1);
    const __half2 h2 = *reinterpret_cast<const __half2*>(&uv2);
    const __half2 h3 = *reinterpret_cast<const __half2*>(&uv3);

    const float v0 = fmaf(__low2float(h0), sc_l, sh_l) + fmaf(__high2float(h0), sc_s, sh_s);
    const float v1 = fmaf(__low2float(h1), sc_l, sh_l) + fmaf(__high2float(h1), sc_s, sh_s);
    const float v2 = fmaf(__low2float(h2), sc_l, sh_l) + fmaf(__high2float(h2), sc_s, sh_s);
    const float v3 = fmaf(__low2float(h3), sc_l, sh_l) + fmaf(__high2float(h3), sc_s, sh_s);

    f32x4 r;
    r.x = 0.5f * v0 * (1.0f + erff(v0 * 0.70710678118654752f));
    r.y = 0.5f * v1 * (1.0f + erff(v1 * 0.70710678118654752f));
    r.z = 0.5f * v2 * (1.0f + erff(v2 * 0.70710678118654752f));
    r.w = 0.5f * v3 * (1.0f + erff(v3 * 0.70710678118654752f));
    __builtin_nontemporal_store(r, out + i);
}

extern "C" void kernel_launch(void* const* d_in, const int* in_sizes, int n_in,
                              void* d_out, int out_size, void* d_ws, size_t ws_size,
                              hipStream_t stream) {
    const float* x        = (const float*)d_in[0];
    const float* w_lk     = (const float*)d_in[1];
    const float* gamma_lk = (const float*)d_in[2];
    const float* beta_lk  = (const float*)d_in[3];
    const float* w_sk     = (const float*)d_in[4];
    const float* gamma_sk = (const float*)d_in[5];
    const float* beta_sk  = (const float*)d_in[6];
    float* out = (float*)d_out;

    float* partial = (float*)d_ws;                       // CH*NB*2*4 floats (393 KB)
    uint2* yls     = (uint2*)(partial + CH * NB * 2 * 4);// 50 MB packed fp16 pairs

    conv_stats_kernel<<<NB * CH, 128, 0, stream>>>(x, w_lk, w_sk, yls, partial);
    apply_kernel<<<NB * CH, 256, 0, stream>>>(
        (const u32x4*)yls, partial, gamma_lk, beta_lk, gamma_sk, beta_sk,
        (f32x4*)out);
}